// Round 1
// baseline (3017.220 us; speedup 1.0000x reference)
//
#include <hip/hip_runtime.h>
#include <math.h>

#define B_  4
#define S_  2048
#define D_  1024
#define H_  16
#define DH_ 64
#define LN_EPS 1e-6f

// ---------------- block-wide all-reduce (256 threads = 4 waves of 64) -------
__device__ __forceinline__ float block_allreduce(float v, bool is_max, float* sbuf) {
  #pragma unroll
  for (int o = 32; o > 0; o >>= 1) {
    float other = __shfl_down(v, o, 64);
    v = is_max ? fmaxf(v, other) : (v + other);
  }
  __syncthreads();                       // protect sbuf reuse across calls
  if ((threadIdx.x & 63) == 0) sbuf[threadIdx.x >> 6] = v;
  __syncthreads();
  float r = sbuf[0];
  #pragma unroll
  for (int w = 1; w < 4; ++w) r = is_max ? fmaxf(r, sbuf[w]) : (r + sbuf[w]);
  return r;
}

// ---------------- GEMM: C = A@W + bias (+resid) -----------------------------
// A:[M,K] row-major, W:[K,N] row-major, C:[M,N]. Tile 64x64, BK=16, 4x4/thread.
__global__ __launch_bounds__(256) void gemm_bias_kernel(
    const float* __restrict__ A, const float* __restrict__ W,
    const float* __restrict__ bias, const float* __restrict__ resid,
    float* __restrict__ C, int M, int N, int K)
{
  __shared__ float As[16][65];   // As[k][m] (transposed), +1 pad
  __shared__ float Bs[16][64];   // Bs[k][n]
  const int tid = threadIdx.x;
  const int tx = tid & 15, ty = tid >> 4;
  const int bm = blockIdx.y * 64, bn = blockIdx.x * 64;
  const int am  = tid >> 2;          // 0..63
  const int ak  = (tid & 3) << 2;    // 0,4,8,12
  const int bk  = tid >> 4;          // 0..15
  const int bn4 = (tid & 15) << 2;   // 0..60
  float acc[4][4] = {};
  for (int k0 = 0; k0 < K; k0 += 16) {
    float4 a = *(const float4*)(A + (size_t)(bm + am) * K + k0 + ak);
    float4 b = *(const float4*)(W + (size_t)(k0 + bk) * N + bn + bn4);
    As[ak+0][am] = a.x; As[ak+1][am] = a.y; As[ak+2][am] = a.z; As[ak+3][am] = a.w;
    *(float4*)(&Bs[bk][bn4]) = b;
    __syncthreads();
    #pragma unroll
    for (int kk = 0; kk < 16; ++kk) {
      float a0 = As[kk][ty*4+0], a1 = As[kk][ty*4+1];
      float a2 = As[kk][ty*4+2], a3 = As[kk][ty*4+3];
      float4 bv = *(float4*)(&Bs[kk][tx*4]);
      acc[0][0] += a0*bv.x; acc[0][1] += a0*bv.y; acc[0][2] += a0*bv.z; acc[0][3] += a0*bv.w;
      acc[1][0] += a1*bv.x; acc[1][1] += a1*bv.y; acc[1][2] += a1*bv.z; acc[1][3] += a1*bv.w;
      acc[2][0] += a2*bv.x; acc[2][1] += a2*bv.y; acc[2][2] += a2*bv.z; acc[2][3] += a2*bv.w;
      acc[3][0] += a3*bv.x; acc[3][1] += a3*bv.y; acc[3][2] += a3*bv.z; acc[3][3] += a3*bv.w;
    }
    __syncthreads();
  }
  float4 bb = *(const float4*)(bias + bn + tx*4);
  #pragma unroll
  for (int i = 0; i < 4; ++i) {
    int m = bm + ty*4 + i;
    float4 o;
    o.x = acc[i][0] + bb.x; o.y = acc[i][1] + bb.y;
    o.z = acc[i][2] + bb.z; o.w = acc[i][3] + bb.w;
    if (resid) {
      float4 r = *(const float4*)(resid + (size_t)m * N + bn + tx*4);
      o.x += r.x; o.y += r.y; o.z += r.z; o.w += r.w;
    }
    *(float4*)(C + (size_t)m * N + bn + tx*4) = o;
  }
}

// ---------------- scores: raw causal scores into weights buffer -------------
// W[b,h,q,k] = dot_d(Q[b,q,h,d], K[b,k,h,d]) / 8  for k<=q (others untouched)
__global__ __launch_bounds__(256) void scores_kernel(
    const float* __restrict__ Q, const float* __restrict__ Km,
    float* __restrict__ Wout)
{
  const int kt = blockIdx.x, qt = blockIdx.y;
  if (kt > qt) return;                       // fully-masked tile
  const int bh = blockIdx.z;
  const int b = bh >> 4, h = bh & 15;
  const int q0 = qt * 64, k0 = kt * 64;
  __shared__ float Qs[64][68];   // [q][d]
  __shared__ float Ks[64][68];   // [d][k]  (transposed)
  const int tid = threadIdx.x;
  const int tx = tid & 15, ty = tid >> 4;
  const float* Qbase = Q  + ((size_t)b * S_ + q0) * D_ + h * DH_;
  const float* Kbase = Km + ((size_t)b * S_ + k0) * D_ + h * DH_;
  #pragma unroll
  for (int i = 0; i < 4; ++i) {
    int idx = tid + i * 256;
    int r = idx >> 4;            // 0..63
    int c4 = (idx & 15) << 2;    // 0..60
    float4 qv = *(const float4*)(Qbase + (size_t)r * D_ + c4);
    *(float4*)(&Qs[r][c4]) = qv;
    float4 kv = *(const float4*)(Kbase + (size_t)r * D_ + c4);
    Ks[c4+0][r] = kv.x; Ks[c4+1][r] = kv.y; Ks[c4+2][r] = kv.z; Ks[c4+3][r] = kv.w;
  }
  __syncthreads();
  float acc[4][4] = {};
  #pragma unroll 8
  for (int d = 0; d < 64; ++d) {
    float4 kv = *(float4*)(&Ks[d][tx*4]);
    float a0 = Qs[ty*4+0][d], a1 = Qs[ty*4+1][d];
    float a2 = Qs[ty*4+2][d], a3 = Qs[ty*4+3][d];
    acc[0][0] += a0*kv.x; acc[0][1] += a0*kv.y; acc[0][2] += a0*kv.z; acc[0][3] += a0*kv.w;
    acc[1][0] += a1*kv.x; acc[1][1] += a1*kv.y; acc[1][2] += a1*kv.z; acc[1][3] += a1*kv.w;
    acc[2][0] += a2*kv.x; acc[2][1] += a2*kv.y; acc[2][2] += a2*kv.z; acc[2][3] += a2*kv.w;
    acc[3][0] += a3*kv.x; acc[3][1] += a3*kv.y; acc[3][2] += a3*kv.z; acc[3][3] += a3*kv.w;
  }
  const float scale = 0.125f;   // 1/sqrt(64)
  float* Wrow = Wout + ((size_t)bh * S_ + q0) * S_ + k0;
  if (kt < qt) {                // fully unmasked tile
    #pragma unroll
    for (int i = 0; i < 4; ++i) {
      float4 o;
      o.x = acc[i][0]*scale; o.y = acc[i][1]*scale;
      o.z = acc[i][2]*scale; o.w = acc[i][3]*scale;
      *(float4*)(Wrow + (size_t)(ty*4+i) * S_ + tx*4) = o;
    }
  } else {                      // diagonal tile: per-element causal guard
    #pragma unroll
    for (int i = 0; i < 4; ++i) {
      int qg = q0 + ty*4 + i;
      #pragma unroll
      for (int j = 0; j < 4; ++j) {
        int kg = k0 + tx*4 + j;
        if (kg <= qg) Wrow[(size_t)(ty*4+i) * S_ + tx*4 + j] = acc[i][j] * scale;
      }
    }
  }
}

// ---------------- softmax: in-place over each row, zeros above diagonal -----
__global__ __launch_bounds__(256) void softmax_kernel(float* __restrict__ Wbuf) {
  const int q = blockIdx.x;
  float* row = Wbuf + ((size_t)blockIdx.y * S_ + q) * S_;
  const int valid = q + 1;
  __shared__ float sbuf[4];
  float v[8];
  float lmax = -INFINITY;
  #pragma unroll
  for (int i = 0; i < 8; ++i) {
    int k = threadIdx.x + (i << 8);
    v[i] = (k < valid) ? row[k] : -INFINITY;
    lmax = fmaxf(lmax, v[i]);
  }
  float m = block_allreduce(lmax, true, sbuf);
  float lsum = 0.f;
  #pragma unroll
  for (int i = 0; i < 8; ++i) {
    int k = threadIdx.x + (i << 8);
    v[i] = (k < valid) ? __expf(v[i] - m) : 0.f;   // masked -> exactly 0 (ref: exp(-1e9) underflows)
    lsum += v[i];
  }
  float s = block_allreduce(lsum, false, sbuf);
  float inv = 1.f / s;
  #pragma unroll
  for (int i = 0; i < 8; ++i) {
    int k = threadIdx.x + (i << 8);
    row[k] = v[i] * inv;
  }
}

// ---------------- PV: attn[b,q,h,:] = sum_k W[b,h,q,k] * V[b,k,h,:] ---------
__global__ __launch_bounds__(256) void pv_kernel(
    const float* __restrict__ Wbuf, const float* __restrict__ V,
    float* __restrict__ Attn)
{
  const int qt = blockIdx.x, h = blockIdx.y, b = blockIdx.z;
  const int q0 = qt * 64;
  __shared__ float Ws[64][68];   // [q][k]
  __shared__ float Vs[64][68];   // [k][d]
  const int tid = threadIdx.x;
  const int tx = tid & 15, ty = tid >> 4;
  float acc[4][4] = {};
  const size_t wbase = (((size_t)b * H_ + h) * S_ + q0) * S_;
  const float* Vbase = V + (size_t)b * S_ * D_ + h * DH_;
  for (int kt = 0; kt <= qt; ++kt) {       // causal: masked weights are exactly 0
    int k0 = kt * 64;
    #pragma unroll
    for (int i = 0; i < 4; ++i) {
      int idx = tid + i * 256;
      int r = idx >> 4, c4 = (idx & 15) << 2;
      *(float4*)(&Ws[r][c4]) = *(const float4*)(Wbuf + wbase + (size_t)r * S_ + k0 + c4);
      *(float4*)(&Vs[r][c4]) = *(const float4*)(Vbase + (size_t)(k0 + r) * D_ + c4);
    }
    __syncthreads();
    #pragma unroll 8
    for (int kk = 0; kk < 64; ++kk) {
      float4 vv = *(float4*)(&Vs[kk][tx*4]);
      float w0 = Ws[ty*4+0][kk], w1 = Ws[ty*4+1][kk];
      float w2 = Ws[ty*4+2][kk], w3 = Ws[ty*4+3][kk];
      acc[0][0] += w0*vv.x; acc[0][1] += w0*vv.y; acc[0][2] += w0*vv.z; acc[0][3] += w0*vv.w;
      acc[1][0] += w1*vv.x; acc[1][1] += w1*vv.y; acc[1][2] += w1*vv.z; acc[1][3] += w1*vv.w;
      acc[2][0] += w2*vv.x; acc[2][1] += w2*vv.y; acc[2][2] += w2*vv.z; acc[2][3] += w2*vv.w;
      acc[3][0] += w3*vv.x; acc[3][1] += w3*vv.y; acc[3][2] += w3*vv.z; acc[3][3] += w3*vv.w;
    }
    __syncthreads();
  }
  #pragma unroll
  for (int i = 0; i < 4; ++i) {
    float4 o = { acc[i][0], acc[i][1], acc[i][2], acc[i][3] };
    *(float4*)(Attn + ((size_t)b * S_ + q0 + ty*4 + i) * D_ + h * DH_ + tx*4) = o;
  }
}

// ---------------- LayerNorm over last dim (1024) ----------------------------
__global__ __launch_bounds__(256) void ln_kernel(
    const float* __restrict__ R, const float* __restrict__ gamma,
    const float* __restrict__ beta, float* __restrict__ Out)
{
  const int row = blockIdx.x;
  const float* x = R + (size_t)row * D_;
  __shared__ float sbuf[4];
  float4 xv = *(const float4*)(x + threadIdx.x * 4);
  float s  = xv.x + xv.y + xv.z + xv.w;
  float ss = xv.x*xv.x + xv.y*xv.y + xv.z*xv.z + xv.w*xv.w;
  float tot  = block_allreduce(s,  false, sbuf);
  float tot2 = block_allreduce(ss, false, sbuf);
  float mu  = tot  * (1.f / D_);
  float var = tot2 * (1.f / D_) - mu * mu;
  float inv = rsqrtf(var + LN_EPS);
  float4 g  = *(const float4*)(gamma + threadIdx.x * 4);
  float4 be = *(const float4*)(beta  + threadIdx.x * 4);
  float4 o;
  o.x = (xv.x - mu) * inv * g.x + be.x;
  o.y = (xv.y - mu) * inv * g.y + be.y;
  o.z = (xv.z - mu) * inv * g.z + be.z;
  o.w = (xv.w - mu) * inv * g.w + be.w;
  *(float4*)(Out + (size_t)row * D_ + threadIdx.x * 4) = o;
}

extern "C" void kernel_launch(void* const* d_in, const int* in_sizes, int n_in,
                              void* d_out, int out_size, void* d_ws, size_t ws_size,
                              hipStream_t stream) {
  const float* X     = (const float*)d_in[0];
  const float* Wq    = (const float*)d_in[1];
  const float* bq    = (const float*)d_in[2];
  const float* Wk    = (const float*)d_in[3];
  const float* bk    = (const float*)d_in[4];
  const float* Wv    = (const float*)d_in[5];
  const float* bv    = (const float*)d_in[6];
  const float* Wo    = (const float*)d_in[7];
  const float* bo    = (const float*)d_in[8];
  const float* gamma = (const float*)d_in[9];
  const float* beta  = (const float*)d_in[10];

  float* out     = (float*)d_out;
  float* normed  = out;                              // [B,S,D]
  float* weights = out + (size_t)B_ * S_ * D_;       // [B,H,S,S]

  const size_t sz = (size_t)B_ * S_ * D_;            // 8388608 floats
  float* ws   = (float*)d_ws;
  float* Qb   = ws;
  float* Kb   = ws + sz;
  float* Vb   = ws + 2 * sz;
  float* Attn  = Qb;   // Q dead after scores
  float* Resid = Kb;   // K dead after scores

  dim3 blk(256);
  dim3 gemm_grid(D_ / 64, (B_ * S_) / 64);           // (16, 128)
  gemm_bias_kernel<<<gemm_grid, blk, 0, stream>>>(X, Wq, bq, nullptr, Qb, B_*S_, D_, D_);
  gemm_bias_kernel<<<gemm_grid, blk, 0, stream>>>(X, Wk, bk, nullptr, Kb, B_*S_, D_, D_);
  gemm_bias_kernel<<<gemm_grid, blk, 0, stream>>>(X, Wv, bv, nullptr, Vb, B_*S_, D_, D_);

  dim3 sc_grid(S_ / 64, S_ / 64, B_ * H_);           // (32, 32, 64)
  scores_kernel<<<sc_grid, blk, 0, stream>>>(Qb, Kb, weights);

  softmax_kernel<<<dim3(S_, B_ * H_), blk, 0, stream>>>(weights);

  pv_kernel<<<dim3(S_ / 64, H_, B_), blk, 0, stream>>>(weights, Vb, Attn);

  gemm_bias_kernel<<<gemm_grid, blk, 0, stream>>>(Attn, Wo, bo, X, Resid, B_*S_, D_, D_);

  ln_kernel<<<dim3(B_ * S_), blk, 0, stream>>>(Resid, gamma, beta, normed);
}